// Round 18
// baseline (56.977 us; speedup 1.0000x reference)
//
#include <hip/hip_runtime.h>
#include <math.h>

#define BDIM 512
#define DDIM 512

constexpr float EPS   = 1e-6f;
constexpr float HEPS  = 0.5e-6f;
constexpr float LN2   = 0.6931471805599453f;
constexpr float LOG2E = 1.4426950408889634f;

__device__ __forceinline__ float wave_reduce_sum(float v) {
  #pragma unroll
  for (int o = 32; o > 0; o >>= 1) v += __shfl_down(v, o, 64);
  return v;
}
__device__ __forceinline__ float wave_reduce_max(float v) {
  #pragma unroll
  for (int o = 32; o > 0; o >>= 1) v = fmaxf(v, __shfl_down(v, o, 64));
  return v;
}

// ---------------------------------------------------------------------------
// Kernel 1: per-row l2-normalize mu; SoA outputs nA/sA/nB/sB
// (sX = 0.5*sigma + 0.5*EPS so sv = sA+sB), ld, mrow.
// ---------------------------------------------------------------------------
__global__ __launch_bounds__(256) void prep_kernel(
    const float* __restrict__ mu1, const float* __restrict__ s1,
    const float* __restrict__ mu2, const float* __restrict__ s2,
    float* __restrict__ nA, float* __restrict__ sA,
    float* __restrict__ nB, float* __restrict__ sB,
    float* __restrict__ ld,         // ld1 at 0, ld2 at +B
    float* __restrict__ mrow) {     // m1 at 0, m2 at +B
  const int r = blockIdx.x;
  const int which = blockIdx.y;
  const float* __restrict__ mu = which ? mu2 : mu1;
  const float* __restrict__ sg = which ? s2 : s1;
  float* __restrict__ nout = which ? nB : nA;
  float* __restrict__ sout = which ? sB : sA;
  const int t = threadIdx.x;

  const float a  = mu[r * DDIM + t];
  const float b  = mu[r * DDIM + t + 256];
  const float sa = sg[r * DDIM + t];
  const float sb = sg[r * DDIM + t + 256];

  float v0 = a * a + b * b;
  float v1 = __log2f(sa + EPS) + __log2f(sb + EPS);
  float v2 = sa + sb;

  __shared__ float red[3][4];
  __shared__ float sinv;
  const int wid = t >> 6, lane = t & 63;
  v0 = wave_reduce_sum(v0);
  v1 = wave_reduce_sum(v1);
  v2 = wave_reduce_sum(v2);
  if (lane == 0) { red[0][wid] = v0; red[1][wid] = v1; red[2][wid] = v2; }
  __syncthreads();
  if (t == 0) {
    float sq = red[0][0] + red[0][1] + red[0][2] + red[0][3];
    float lg = red[1][0] + red[1][1] + red[1][2] + red[1][3];
    float sm = red[2][0] + red[2][1] + red[2][2] + red[2][3];
    ld[which * BDIM + r]   = LN2 * lg;
    mrow[which * BDIM + r] = sm * (1.0f / DDIM);
    sinv = 1.0f / fmaxf(sqrtf(sq), 1e-12f);
  }
  __syncthreads();
  const float inv = sinv;
  nout[r * DDIM + t]       = a * inv;
  nout[r * DDIM + t + 256] = b * inv;
  sout[r * DDIM + t]       = fmaf(0.5f, sa, HEPS);
  sout[r * DDIM + t + 256] = fmaf(0.5f, sb, HEPS);
}

// ---------------------------------------------------------------------------
// Kernel 2: B^2*D partial pass — R17 design with the chunk-count FIX:
// 4 chunks x 16 d = the block's 64-d slice (R17's c<8 swept 128 d and
// read out of bounds -> NaN). LDS as float2 rows (stride 9 f2 = 8 data
// + 1 pad): 18432 B total -> high blocks/CU; b64 operand reads cut live
// regs (target ~100 VGPR -> 5 waves/SIMD). Bank audit: A-reads = 4-row
// broadcast (free); B-reads 16 rows x 18-bank stride -> 16 distinct
// banks (free). Scalar paired-rcp math, 4x4/thread, grid (8,8,8).
// ---------------------------------------------------------------------------
__global__ __launch_bounds__(256) void bd_kernel(
    const float* __restrict__ nA, const float* __restrict__ sA,
    const float* __restrict__ nB, const float* __restrict__ sB,
    float* __restrict__ bdp, float* __restrict__ dacp) {
  // f2 offsets: An 0, As 576, Bn 1152, Bs 1728; 64 rows x 9 f2 each
  __shared__ __align__(16) float2 lds2[2304];   // 18432 B

  const int t  = threadIdx.x;
  const int i0 = blockIdx.y * 64, j0 = blockIdx.x * 64;
  const int z  = blockIdx.z;       // 0..7 (64-d slice, staged as 4x16)
  const int ti = t >> 4;           // 0..15
  const int tj = t & 15;           // 0..15

  float t1[4][4]  = {};
  float lda[4][4] = {};
  float dac[4][4] = {};

  const int srow = t >> 2;         // staging row 0..63
  const int sc4  = t & 3;          // staging f4-col 0..3

  for (int c = 0; c < 4; ++c) {    // 4 x 16-d chunks = 64-d slice (FIXED)
    const int db = z * 64 + c * 16;
    if (c) __syncthreads();        // guard LDS before restage
    // ---- stage 16-d chunk: per array 64 rows x 4 f4 = 256 f4 (1/thread) --
    {
      const float4 v = *(const float4*)&nA[(i0 + srow) * DDIM + db + sc4 * 4];
      lds2[srow * 9 + sc4 * 2]     = make_float2(v.x, v.y);
      lds2[srow * 9 + sc4 * 2 + 1] = make_float2(v.z, v.w);
    }
    {
      const float4 v = *(const float4*)&sA[(i0 + srow) * DDIM + db + sc4 * 4];
      lds2[576 + srow * 9 + sc4 * 2]     = make_float2(v.x, v.y);
      lds2[576 + srow * 9 + sc4 * 2 + 1] = make_float2(v.z, v.w);
    }
    {
      const float4 v = *(const float4*)&nB[(j0 + srow) * DDIM + db + sc4 * 4];
      lds2[1152 + srow * 9 + sc4 * 2]     = make_float2(v.x, v.y);
      lds2[1152 + srow * 9 + sc4 * 2 + 1] = make_float2(v.z, v.w);
    }
    {
      const float4 v = *(const float4*)&sB[(j0 + srow) * DDIM + db + sc4 * 4];
      lds2[1728 + srow * 9 + sc4 * 2]     = make_float2(v.x, v.y);
      lds2[1728 + srow * 9 + sc4 * 2 + 1] = make_float2(v.z, v.w);
    }
    __syncthreads();

    // ---- compute: 2 m-batches of 4 f2 (8 d each) ----
    for (int g = 0; g < 2; ++g) {
      float m[4][4] = {{1.f,1.f,1.f,1.f},{1.f,1.f,1.f,1.f},
                       {1.f,1.f,1.f,1.f},{1.f,1.f,1.f,1.f}};
      #pragma unroll
      for (int k = 0; k < 4; ++k) {
        const int dd = g * 4 + k;      // f2 index 0..7 (one d-pair)
        float2 Bn2[4], Bs2[4];
        #pragma unroll
        for (int qj = 0; qj < 4; ++qj)
          Bn2[qj] = lds2[1152 + (tj + 16 * qj) * 9 + dd];
        #pragma unroll
        for (int qj = 0; qj < 4; ++qj)
          Bs2[qj] = lds2[1728 + (tj + 16 * qj) * 9 + dd];
        #pragma unroll
        for (int qi = 0; qi < 4; ++qi) {
          const float2 An2 = lds2[(ti + 16 * qi) * 9 + dd];
          const float2 As2 = lds2[576 + (ti + 16 * qi) * 9 + dd];
          #pragma unroll
          for (int qj = 0; qj < 4; ++qj) {
            const float sv0 = As2.x + Bs2[qj].x;
            const float sv1 = As2.y + Bs2[qj].y;
            const float svp = sv0 * sv1;
            const float df0 = An2.x - Bn2[qj].x;
            const float df1 = An2.y - Bn2[qj].y;
            float num = (df0 * df0) * sv1;
            num = fmaf(df1 * df1, sv0, num);
            t1[qi][qj]  = fmaf(num, __builtin_amdgcn_rcpf(svp), t1[qi][qj]);
            m[qi][qj]  *= svp;
            dac[qi][qj] = fmaf(An2.x, Bn2[qj].x, dac[qi][qj]);
            dac[qi][qj] = fmaf(An2.y, Bn2[qj].y, dac[qi][qj]);
          }
        }
      }
      #pragma unroll
      for (int qi = 0; qi < 4; ++qi)
        #pragma unroll
        for (int qj = 0; qj < 4; ++qj)
          lda[qi][qj] += __log2f(m[qi][qj]);
    }
  }

  // ---- per-thread partial writes (plane z): folded bd partial + dac ----
  const size_t zb = (size_t)z * BDIM * BDIM;
  #pragma unroll
  for (int qi = 0; qi < 4; ++qi) {
    #pragma unroll
    for (int qj = 0; qj < 4; ++qj) {
      const size_t o = zb + (size_t)(i0 + 16 * qi + ti) * BDIM
                          + j0 + 16 * qj + tj;
      bdp[o]  = fmaf(0.125f, t1[qi][qj], 0.5f * LN2 * lda[qi][qj]);
      dacp[o] = dac[qi][qj];
    }
  }
}

// ---------------------------------------------------------------------------
// Kernel 3: combine z-partials. bd = sum(bdp) - 0.25*(l1+l2). sim<=1 ->
// fixed-max LSE: E = exp(sc*(sim-1)); lse = sc + ln(sum E). No max passes.
// ---------------------------------------------------------------------------
__global__ __launch_bounds__(256) void combine_kernel(
    const float* __restrict__ bdp, const float* __restrict__ dacp,
    const float* __restrict__ ld, const float* __restrict__ lscale,
    float* __restrict__ E, float* __restrict__ pmaxf,
    float* __restrict__ pdiag, float* __restrict__ lse_row,
    float* __restrict__ dlog) {
  const int i = blockIdx.x;
  const int t = threadIdx.x;
  const float l1 = ld[i];
  const float sc = *lscale;
  float rmax = 0.f;
  float esum = 0.f;
  #pragma unroll
  for (int q = 0; q < 2; ++q) {
    const int j = t + q * 256;
    const size_t o = (size_t)i * BDIM + j;
    float bsum = 0.f, dac = 0.f;
    #pragma unroll
    for (int zz = 0; zz < 8; ++zz) {
      const size_t idx = (size_t)zz * BDIM * BDIM + o;
      bsum += bdp[idx]; dac += dacp[idx];
    }
    const float bd = bsum - 0.25f * (l1 + ld[BDIM + j]);
    const float sv = exp2f(bd * (-LOG2E / (float)DDIM));   // sim in (0,1]
    const float e  = exp2f(sc * (sv - 1.0f) * LOG2E);      // E in (0,1]
    E[o] = e;
    esum += e;
    const float p = exp2f((2.0f * LOG2E) * dac);
    if (j == i) { pdiag[i] = p; dlog[i] = sc * sv; }
    else        rmax = fmaxf(rmax, p);
  }
  __shared__ float red[4];
  const int wid = t >> 6, lane = t & 63;

  float wm = wave_reduce_max(rmax);
  if (lane == 0) red[wid] = wm;
  __syncthreads();
  if (t == 0) pmaxf[i] = fmaxf(fmaxf(red[0], red[1]), fmaxf(red[2], red[3]));
  __syncthreads();

  float rs = wave_reduce_sum(esum);
  if (lane == 0) red[wid] = rs;
  __syncthreads();
  if (t == 0)
    lse_row[i] = sc + LN2 * __log2f(red[0] + red[1] + red[2] + red[3]);
}

// ---------------------------------------------------------------------------
// Kernel 4: column sums of E via coalesced row sweep (16 blocks x 32 rows).
// ---------------------------------------------------------------------------
__global__ __launch_bounds__(256) void colsum_kernel(
    const float* __restrict__ E, float* __restrict__ colpart) {
  const int k = blockIdx.x;        // 0..15
  const int t = threadIdx.x;
  float a0 = 0.f, a1 = 0.f;
  #pragma unroll 4
  for (int r = 0; r < 32; ++r) {
    const int row = k * 32 + r;
    a0 += E[row * BDIM + t];
    a1 += E[row * BDIM + t + 256];
  }
  colpart[k * BDIM + t]       = a0;
  colpart[k * BDIM + t + 256] = a1;
}

// ---------------------------------------------------------------------------
// Kernel 5: final reductions -> 3 scalars (lse_col folded in).
// ---------------------------------------------------------------------------
__global__ __launch_bounds__(512) void final_kernel(
    const float* __restrict__ pdiag, const float* __restrict__ pmaxf,
    const float* __restrict__ mrow, const float* __restrict__ lse_row,
    const float* __restrict__ colpart, const float* __restrict__ dlog,
    const float* __restrict__ lscale, float* __restrict__ out) {
  const int t = threadIdx.x;  // 0..511
  const float sc = *lscale;
  float cs = 0.f;
  #pragma unroll
  for (int k = 0; k < 16; ++k) cs += colpart[k * BDIM + t];
  const float lse_col = sc + LN2 * __log2f(cs);

  const float pm = pmaxf[t];
  const float u  = exp2f(-(pdiag[t] / pm) * LOG2E);   // exp(-diag/negmax)
  const float as = 0.5f * (mrow[t] + mrow[BDIM + t]);

  float vals[6];
  vals[0] = u;
  vals[1] = u * u;
  vals[2] = as * as;
  vals[3] = u * as;
  vals[4] = lse_row[t] - dlog[t];
  vals[5] = lse_col - dlog[t];

  __shared__ float red[6][8];
  const int wid = t >> 6, lane = t & 63;
  #pragma unroll
  for (int k = 0; k < 6; ++k) {
    const float v = wave_reduce_sum(vals[k]);
    if (lane == 0) red[k][wid] = v;
  }
  __syncthreads();
  if (t == 0) {
    float s[6];
    #pragma unroll
    for (int k = 0; k < 6; ++k) {
      float a = 0.f;
      #pragma unroll
      for (int w = 0; w < 8; ++w) a += red[k][w];
      s[k] = a;
    }
    const float mean_u = s[0] * (1.0f / BDIM);
    const float cosv = s[3] / fmaxf(sqrtf(s[1]) * sqrtf(s[2]), 1e-24f);
    out[0] = 0.5f * (s[4] + s[5]) * (1.0f / BDIM);  // loss_pro
    out[1] = 2.4f * (1.0f - cosv);                  // loss_rank * 2.4
    out[2] = 0.5f * mean_u;                         // var_loss
  }
}

extern "C" void kernel_launch(void* const* d_in, const int* in_sizes, int n_in,
                              void* d_out, int out_size, void* d_ws, size_t ws_size,
                              hipStream_t stream) {
  const float* mu1 = (const float*)d_in[0];
  const float* s1  = (const float*)d_in[1];
  const float* mu2 = (const float*)d_in[2];
  const float* s2  = (const float*)d_in[3];
  const float* lsc = (const float*)d_in[4];
  float* out = (float*)d_out;

  float* ws      = (float*)d_ws;
  float* nA      = ws;                                // 1MB each
  float* sA      = nA + BDIM * DDIM;
  float* nB      = sA + BDIM * DDIM;
  float* sB      = nB + BDIM * DDIM;
  float* E       = sB + BDIM * DDIM;                  // 1MB
  float* bdp     = E + BDIM * BDIM;                   // 8 * 1MB
  float* dacp    = bdp + 8 * BDIM * BDIM;             // 8 * 1MB
  float* ld      = dacp + 8 * BDIM * BDIM;            // 2*512
  float* mrow    = ld + 2 * BDIM;                     // 2*512
  float* pmaxf   = mrow + 2 * BDIM;                   // 512
  float* pdiag   = pmaxf + BDIM;                      // 512
  float* lse_row = pdiag + BDIM;                      // 512
  float* dlog    = lse_row + BDIM;                    // 512
  float* colpart = dlog + BDIM;                       // 16*512

  prep_kernel<<<dim3(BDIM, 2), 256, 0, stream>>>(mu1, s1, mu2, s2, nA, sA,
                                                 nB, sB, ld, mrow);
  bd_kernel<<<dim3(8, 8, 8), 256, 0, stream>>>(nA, sA, nB, sB, bdp, dacp);
  combine_kernel<<<BDIM, 256, 0, stream>>>(bdp, dacp, ld, lsc, E,
                                           pmaxf, pdiag, lse_row, dlog);
  colsum_kernel<<<16, 256, 0, stream>>>(E, colpart);
  final_kernel<<<1, 512, 0, stream>>>(pdiag, pmaxf, mrow, lse_row, colpart,
                                      dlog, lsc, out);
}

// Round 19
// 51.340 us; speedup vs baseline: 1.1098x; 1.1098x over previous
//
#include <hip/hip_runtime.h>
#include <math.h>

#define BDIM 512
#define DDIM 512

constexpr float EPS   = 1e-6f;
constexpr float HEPS  = 0.5e-6f;
constexpr float LN2   = 0.6931471805599453f;
constexpr float LOG2E = 1.4426950408889634f;

__device__ __forceinline__ float wave_reduce_sum(float v) {
  #pragma unroll
  for (int o = 32; o > 0; o >>= 1) v += __shfl_down(v, o, 64);
  return v;
}
__device__ __forceinline__ float wave_reduce_max(float v) {
  #pragma unroll
  for (int o = 32; o > 0; o >>= 1) v = fmaxf(v, __shfl_down(v, o, 64));
  return v;
}

// ---------------------------------------------------------------------------
// Kernel 1: per-row l2-normalize mu; SoA outputs nA/sA/nB/sB
// (sX = 0.5*sigma + 0.5*EPS so sv = sA+sB), ld, mrow.
// ---------------------------------------------------------------------------
__global__ __launch_bounds__(256) void prep_kernel(
    const float* __restrict__ mu1, const float* __restrict__ s1,
    const float* __restrict__ mu2, const float* __restrict__ s2,
    float* __restrict__ nA, float* __restrict__ sA,
    float* __restrict__ nB, float* __restrict__ sB,
    float* __restrict__ ld,         // ld1 at 0, ld2 at +B
    float* __restrict__ mrow) {     // m1 at 0, m2 at +B
  const int r = blockIdx.x;
  const int which = blockIdx.y;
  const float* __restrict__ mu = which ? mu2 : mu1;
  const float* __restrict__ sg = which ? s2 : s1;
  float* __restrict__ nout = which ? nB : nA;
  float* __restrict__ sout = which ? sB : sA;
  const int t = threadIdx.x;

  const float a  = mu[r * DDIM + t];
  const float b  = mu[r * DDIM + t + 256];
  const float sa = sg[r * DDIM + t];
  const float sb = sg[r * DDIM + t + 256];

  float v0 = a * a + b * b;
  float v1 = __log2f(sa + EPS) + __log2f(sb + EPS);
  float v2 = sa + sb;

  __shared__ float red[3][4];
  __shared__ float sinv;
  const int wid = t >> 6, lane = t & 63;
  v0 = wave_reduce_sum(v0);
  v1 = wave_reduce_sum(v1);
  v2 = wave_reduce_sum(v2);
  if (lane == 0) { red[0][wid] = v0; red[1][wid] = v1; red[2][wid] = v2; }
  __syncthreads();
  if (t == 0) {
    float sq = red[0][0] + red[0][1] + red[0][2] + red[0][3];
    float lg = red[1][0] + red[1][1] + red[1][2] + red[1][3];
    float sm = red[2][0] + red[2][1] + red[2][2] + red[2][3];
    ld[which * BDIM + r]   = LN2 * lg;
    mrow[which * BDIM + r] = sm * (1.0f / DDIM);
    sinv = 1.0f / fmaxf(sqrtf(sq), 1e-12f);
  }
  __syncthreads();
  const float inv = sinv;
  nout[r * DDIM + t]       = a * inv;
  nout[r * DDIM + t + 256] = b * inv;
  sout[r * DDIM + t]       = fmaf(0.5f, sa, HEPS);
  sout[r * DDIM + t + 256] = fmaf(0.5f, sb, HEPS);
}

// ---------------------------------------------------------------------------
// Kernel 2: B^2*D partial pass — R16 configuration (best measured: 51.5 us
// total). 64x64 tile, 4x4/thread, scalar paired-rcp; 64-d slice staged as
// TWO 32-d chunks (plain s-loop, never unrolled — R13 lesson). LDS 36864 B
// = the 4-blocks/CU tier with b128 operand reads (R18 proved the f2/b64
// re-layout regresses: 2x LDS instrs + over-aggressive VGPR target).
// Stride-9-f4 rows: A reads spread banks, B reads 2-way (free).
// Grid (8,8,8); folded bdp partial + dac.
// ---------------------------------------------------------------------------
__global__ __launch_bounds__(256) void bd_kernel(
    const float* __restrict__ nA, const float* __restrict__ sA,
    const float* __restrict__ nB, const float* __restrict__ sB,
    float* __restrict__ bdp, float* __restrict__ dacp) {
  // f4 offsets: An 0, As 576, Bn 1152, Bs 1728; 64 rows x 9 f4 each
  __shared__ __align__(16) float4 lds[2304];   // 36864 B

  const int t  = threadIdx.x;
  const int i0 = blockIdx.y * 64, j0 = blockIdx.x * 64;
  const int z  = blockIdx.z;       // 0..7 (64-d slice, staged as 2x32)
  const int ti = t >> 4;           // 0..15
  const int tj = t & 15;           // 0..15

  float t1[4][4]  = {};
  float lda[4][4] = {};
  float dac[4][4] = {};

  const float4* __restrict__ pAn = lds + 0    + ti * 9;
  const float4* __restrict__ pAs = lds + 576  + ti * 9;
  const float4* __restrict__ pBn = lds + 1152 + tj * 9;
  const float4* __restrict__ pBs = lds + 1728 + tj * 9;

  for (int s = 0; s < 2; ++s) {    // plain loop — do NOT unroll (R13)
    const int dbase = z * 64 + s * 32;
    if (s) __syncthreads();        // guard LDS before restage
    // ---- stage 32-d chunk: 4 arrays x 64 rows x 8 f4 = 2048 f4 ----
    #pragma unroll
    for (int q = 0; q < 2; ++q) {
      const int idx = q * 256 + t, row = idx >> 3, dc = idx & 7;
      lds[row * 9 + dc] =
          *(const float4*)&nA[(i0 + row) * DDIM + dbase + dc * 4];
    }
    #pragma unroll
    for (int q = 0; q < 2; ++q) {
      const int idx = q * 256 + t, row = idx >> 3, dc = idx & 7;
      lds[576 + row * 9 + dc] =
          *(const float4*)&sA[(i0 + row) * DDIM + dbase + dc * 4];
    }
    #pragma unroll
    for (int q = 0; q < 2; ++q) {
      const int idx = q * 256 + t, row = idx >> 3, dc = idx & 7;
      lds[1152 + row * 9 + dc] =
          *(const float4*)&nB[(j0 + row) * DDIM + dbase + dc * 4];
    }
    #pragma unroll
    for (int q = 0; q < 2; ++q) {
      const int idx = q * 256 + t, row = idx >> 3, dc = idx & 7;
      lds[1728 + row * 9 + dc] =
          *(const float4*)&sB[(j0 + row) * DDIM + dbase + dc * 4];
    }
    __syncthreads();

    // ---- compute: 4 m-batches of 8 d (2 f4 each) ----
    for (int g2 = 0; g2 < 4; ++g2) {
      float m[4][4] = {{1.f,1.f,1.f,1.f},{1.f,1.f,1.f,1.f},
                       {1.f,1.f,1.f,1.f},{1.f,1.f,1.f,1.f}};
      #pragma unroll
      for (int h = 0; h < 2; ++h) {
        const int dc = g2 * 2 + h;
        float4 Bn[4], Bs[4];
        #pragma unroll
        for (int q = 0; q < 4; ++q) Bn[q] = pBn[q * 144 + dc];   // 16r x 9
        #pragma unroll
        for (int q = 0; q < 4; ++q) Bs[q] = pBs[q * 144 + dc];
        #pragma unroll
        for (int qi = 0; qi < 4; ++qi) {
          const float4 An = pAn[qi * 144 + dc];
          const float4 As = pAs[qi * 144 + dc];
          #pragma unroll
          for (int p2 = 0; p2 < 2; ++p2) {   // d-pairs (0,1),(2,3)
            const float an0 = ((const float*)&An)[2 * p2];
            const float an1 = ((const float*)&An)[2 * p2 + 1];
            const float as0 = ((const float*)&As)[2 * p2];
            const float as1 = ((const float*)&As)[2 * p2 + 1];
            #pragma unroll
            for (int qj = 0; qj < 4; ++qj) {
              const float bn0 = ((const float*)&Bn[qj])[2 * p2];
              const float bn1 = ((const float*)&Bn[qj])[2 * p2 + 1];
              const float bs0 = ((const float*)&Bs[qj])[2 * p2];
              const float bs1 = ((const float*)&Bs[qj])[2 * p2 + 1];
              const float sv0 = as0 + bs0;
              const float sv1 = as1 + bs1;
              const float svp = sv0 * sv1;
              const float df0 = an0 - bn0;
              const float df1 = an1 - bn1;
              float num = (df0 * df0) * sv1;
              num = fmaf(df1 * df1, sv0, num);
              t1[qi][qj]  = fmaf(num, __builtin_amdgcn_rcpf(svp), t1[qi][qj]);
              m[qi][qj]  *= svp;
              dac[qi][qj] = fmaf(an0, bn0, dac[qi][qj]);
              dac[qi][qj] = fmaf(an1, bn1, dac[qi][qj]);
            }
          }
        }
      }
      #pragma unroll
      for (int qi = 0; qi < 4; ++qi)
        #pragma unroll
        for (int qj = 0; qj < 4; ++qj)
          lda[qi][qj] += __log2f(m[qi][qj]);
    }
  }

  // ---- per-thread partial writes (plane z): folded bd partial + dac ----
  const size_t zb = (size_t)z * BDIM * BDIM;
  #pragma unroll
  for (int qi = 0; qi < 4; ++qi) {
    #pragma unroll
    for (int qj = 0; qj < 4; ++qj) {
      const size_t o = zb + (size_t)(i0 + 16 * qi + ti) * BDIM
                          + j0 + 16 * qj + tj;
      bdp[o]  = fmaf(0.125f, t1[qi][qj], 0.5f * LN2 * lda[qi][qj]);
      dacp[o] = dac[qi][qj];
    }
  }
}

// ---------------------------------------------------------------------------
// Kernel 3: combine z-partials. bd = sum(bdp) - 0.25*(l1+l2). sim<=1 ->
// fixed-max LSE: E = exp(sc*(sim-1)); lse = sc + ln(sum E). No max passes.
// ---------------------------------------------------------------------------
__global__ __launch_bounds__(256) void combine_kernel(
    const float* __restrict__ bdp, const float* __restrict__ dacp,
    const float* __restrict__ ld, const float* __restrict__ lscale,
    float* __restrict__ E, float* __restrict__ pmaxf,
    float* __restrict__ pdiag, float* __restrict__ lse_row,
    float* __restrict__ dlog) {
  const int i = blockIdx.x;
  const int t = threadIdx.x;
  const float l1 = ld[i];
  const float sc = *lscale;
  float rmax = 0.f;
  float esum = 0.f;
  #pragma unroll
  for (int q = 0; q < 2; ++q) {
    const int j = t + q * 256;
    const size_t o = (size_t)i * BDIM + j;
    float bsum = 0.f, dac = 0.f;
    #pragma unroll
    for (int zz = 0; zz < 8; ++zz) {
      const size_t idx = (size_t)zz * BDIM * BDIM + o;
      bsum += bdp[idx]; dac += dacp[idx];
    }
    const float bd = bsum - 0.25f * (l1 + ld[BDIM + j]);
    const float sv = exp2f(bd * (-LOG2E / (float)DDIM));   // sim in (0,1]
    const float e  = exp2f(sc * (sv - 1.0f) * LOG2E);      // E in (0,1]
    E[o] = e;
    esum += e;
    const float p = exp2f((2.0f * LOG2E) * dac);
    if (j == i) { pdiag[i] = p; dlog[i] = sc * sv; }
    else        rmax = fmaxf(rmax, p);
  }
  __shared__ float red[4];
  const int wid = t >> 6, lane = t & 63;

  float wm = wave_reduce_max(rmax);
  if (lane == 0) red[wid] = wm;
  __syncthreads();
  if (t == 0) pmaxf[i] = fmaxf(fmaxf(red[0], red[1]), fmaxf(red[2], red[3]));
  __syncthreads();

  float rs = wave_reduce_sum(esum);
  if (lane == 0) red[wid] = rs;
  __syncthreads();
  if (t == 0)
    lse_row[i] = sc + LN2 * __log2f(red[0] + red[1] + red[2] + red[3]);
}

// ---------------------------------------------------------------------------
// Kernel 4: column sums of E via coalesced row sweep (16 blocks x 32 rows).
// ---------------------------------------------------------------------------
__global__ __launch_bounds__(256) void colsum_kernel(
    const float* __restrict__ E, float* __restrict__ colpart) {
  const int k = blockIdx.x;        // 0..15
  const int t = threadIdx.x;
  float a0 = 0.f, a1 = 0.f;
  #pragma unroll 4
  for (int r = 0; r < 32; ++r) {
    const int row = k * 32 + r;
    a0 += E[row * BDIM + t];
    a1 += E[row * BDIM + t + 256];
  }
  colpart[k * BDIM + t]       = a0;
  colpart[k * BDIM + t + 256] = a1;
}

// ---------------------------------------------------------------------------
// Kernel 5: final reductions -> 3 scalars (lse_col folded in).
// ---------------------------------------------------------------------------
__global__ __launch_bounds__(512) void final_kernel(
    const float* __restrict__ pdiag, const float* __restrict__ pmaxf,
    const float* __restrict__ mrow, const float* __restrict__ lse_row,
    const float* __restrict__ colpart, const float* __restrict__ dlog,
    const float* __restrict__ lscale, float* __restrict__ out) {
  const int t = threadIdx.x;  // 0..511
  const float sc = *lscale;
  float cs = 0.f;
  #pragma unroll
  for (int k = 0; k < 16; ++k) cs += colpart[k * BDIM + t];
  const float lse_col = sc + LN2 * __log2f(cs);

  const float pm = pmaxf[t];
  const float u  = exp2f(-(pdiag[t] / pm) * LOG2E);   // exp(-diag/negmax)
  const float as = 0.5f * (mrow[t] + mrow[BDIM + t]);

  float vals[6];
  vals[0] = u;
  vals[1] = u * u;
  vals[2] = as * as;
  vals[3] = u * as;
  vals[4] = lse_row[t] - dlog[t];
  vals[5] = lse_col - dlog[t];

  __shared__ float red[6][8];
  const int wid = t >> 6, lane = t & 63;
  #pragma unroll
  for (int k = 0; k < 6; ++k) {
    const float v = wave_reduce_sum(vals[k]);
    if (lane == 0) red[k][wid] = v;
  }
  __syncthreads();
  if (t == 0) {
    float s[6];
    #pragma unroll
    for (int k = 0; k < 6; ++k) {
      float a = 0.f;
      #pragma unroll
      for (int w = 0; w < 8; ++w) a += red[k][w];
      s[k] = a;
    }
    const float mean_u = s[0] * (1.0f / BDIM);
    const float cosv = s[3] / fmaxf(sqrtf(s[1]) * sqrtf(s[2]), 1e-24f);
    out[0] = 0.5f * (s[4] + s[5]) * (1.0f / BDIM);  // loss_pro
    out[1] = 2.4f * (1.0f - cosv);                  // loss_rank * 2.4
    out[2] = 0.5f * mean_u;                         // var_loss
  }
}

extern "C" void kernel_launch(void* const* d_in, const int* in_sizes, int n_in,
                              void* d_out, int out_size, void* d_ws, size_t ws_size,
                              hipStream_t stream) {
  const float* mu1 = (const float*)d_in[0];
  const float* s1  = (const float*)d_in[1];
  const float* mu2 = (const float*)d_in[2];
  const float* s2  = (const float*)d_in[3];
  const float* lsc = (const float*)d_in[4];
  float* out = (float*)d_out;

  float* ws      = (float*)d_ws;
  float* nA      = ws;                                // 1MB each
  float* sA      = nA + BDIM * DDIM;
  float* nB      = sA + BDIM * DDIM;
  float* sB      = nB + BDIM * DDIM;
  float* E       = sB + BDIM * DDIM;                  // 1MB
  float* bdp     = E + BDIM * BDIM;                   // 8 * 1MB
  float* dacp    = bdp + 8 * BDIM * BDIM;             // 8 * 1MB
  float* ld      = dacp + 8 * BDIM * BDIM;            // 2*512
  float* mrow    = ld + 2 * BDIM;                     // 2*512
  float* pmaxf   = mrow + 2 * BDIM;                   // 512
  float* pdiag   = pmaxf + BDIM;                      // 512
  float* lse_row = pdiag + BDIM;                      // 512
  float* dlog    = lse_row + BDIM;                    // 512
  float* colpart = dlog + BDIM;                       // 16*512

  prep_kernel<<<dim3(BDIM, 2), 256, 0, stream>>>(mu1, s1, mu2, s2, nA, sA,
                                                 nB, sB, ld, mrow);
  bd_kernel<<<dim3(8, 8, 8), 256, 0, stream>>>(nA, sA, nB, sB, bdp, dacp);
  combine_kernel<<<BDIM, 256, 0, stream>>>(bdp, dacp, ld, lsc, E,
                                           pmaxf, pdiag, lse_row, dlog);
  colsum_kernel<<<16, 256, 0, stream>>>(E, colpart);
  final_kernel<<<1, 512, 0, stream>>>(pdiag, pmaxf, mrow, lse_row, colpart,
                                      dlog, lsc, out);
}